// Round 6
// baseline (38.007 us; speedup 1.0000x reference)
//
#include <hip/hip_runtime.h>

#define C 256
#define HW 81
#define PITCH 292   // ushorts per pixel row: [4 pad][256 ch][32 pad] (even dword pitch)
#define PITCHD 146  // dwords per pixel row; 146%32=18 -> gather tap bases ~4-apart
#define ZROW 81     // zeroed row index for invalid gather taps

__device__ __forceinline__ float lo_f(unsigned int d) {
  union { unsigned int i; float f; } c; c.i = d << 16; return c.f;
}
__device__ __forceinline__ float hi_f(unsigned int d) {
  union { unsigned int i; float f; } c; c.i = d & 0xffff0000u; return c.f;
}
__device__ __forceinline__ float bf2f(unsigned short u) {
  union { unsigned int i; float f; } c; c.i = ((unsigned int)u) << 16; return c.f;
}
__device__ __forceinline__ unsigned short f2bf(float f) {
  union { float f; unsigned int i; } c; c.f = f;
  return (unsigned short)((c.i + 0x7fffu + ((c.i >> 16) & 1u)) >> 16);
}
__device__ __forceinline__ unsigned int pack2(float a, float b) {
  return (unsigned int)f2bf(a) | ((unsigned int)f2bf(b) << 16);
}

// ---------------------------------------------------------------------------
// R6: DIAGNOSTIC PROBE on the R5 base (27.61us). Phase 2 is executed TWICE
// (k=0..3 real, k=4..7 shadow). Each shadow iteration starts with a memory
// clobber (forces genuine LDS re-reads + full recompute; defeats CSE) and
// keeps its results alive via asm "v" constraints instead of storing.
// Delta(dur) vs 27.6us isolates phase-2's marginal wall cost:
//   <3us: phase 2 minor -> attack phases 0/1/stores next.
//   3-7us: phase 2 ~= model -> missing time is phases 0/1/barriers.
//   >8us: phase 2 dominates -> gather latency-chain theory revives.
//   >>13us: superlinear -> I-fetch/code-size bottleneck.
// Phases 0/1/epilogue byte-identical to R5.
// ---------------------------------------------------------------------------
__global__ __launch_bounds__(1024) void semca_fused(
    const float* __restrict__ x, const float* __restrict__ wk,
    const float* __restrict__ bk, const float* __restrict__ w1,
    const float* __restrict__ gamma, const float* __restrict__ beta,
    const float* __restrict__ mean, const float* __restrict__ var,
    const float* __restrict__ w2, const float* __restrict__ b2,
    const float* __restrict__ wv, const float* __restrict__ bv,
    float* __restrict__ out) {
  __shared__ unsigned short xT[82 * PITCH];   // 47,888 B (row 81 = zeros)
  __shared__ unsigned short k1T[82 * PITCH];  // 47,888 B (row 81 = zeros)
  __shared__ unsigned short vT[18 * PITCH];   // 10,512 B
  __shared__ unsigned short pixtab[228];      //    456 B (premultiplied by PITCH)
  __shared__ float2 bnf[225];                 //  1,800 B  (~106 KiB total)

  const int blk = blockIdx.x;
  const int b = (blk & 7) * 16 + ((blk >> 3) & 15);  // XCD-paired, bijective
  const int s = blk >> 7;
  const int tid = threadIdx.x;
  const float* xb = x + (size_t)b * (C * HW);

  unsigned int* xTd = (unsigned int*)xT;
  unsigned int* k1Td = (unsigned int*)k1T;
  unsigned int* vTd = (unsigned int*)vT;

  // ---- phase 0a: issue ALL x loads first (registers), incremental walk
  float xe[11], xo[11];
  int adr[11];
  {
    int chp = tid / HW;            // single division
    int p = tid - chp * HW;
#pragma unroll
    for (int rep = 0; rep < 10; ++rep) {
      const float* base = xb + (2 * chp) * HW + p;
      xe[rep] = base[0];
      xo[rep] = base[HW];
      adr[rep] = PITCHD * p + 2 + chp;
      chp += 12;                   // advance f by 1024 = 12*81 + 52
      p += 52;
      if (p >= HW) { p -= HW; chp += 1; }
    }
    if (tid < 128) {               // tail item f = 10240 + tid
      int f = 10240 + tid;
      int c2 = f / HW, p2 = f - c2 * HW;
      xe[10] = xb[2 * c2 * HW + p2];
      xo[10] = xb[(2 * c2 + 1) * HW + p2];
      adr[10] = PITCHD * p2 + 2 + c2;
    }
  }

  // ---- phase 0b: independent work under the load shadow
  for (int t = tid; t < 810; t += 1024) {  // x channel-pad zeros
    int p = t / 10, k2 = t - (t / 10) * 10;
    xT[p * PITCH + ((k2 < 4) ? k2 : (256 + k2))] = 0;
  }
  if (tid < PITCHD) {                      // zero row 81 of xT and k1T
    xTd[PITCHD * ZROW + tid] = 0;
    k1Td[PITCHD * ZROW + tid] = 0;
  }
  for (int t = tid; t < 225; t += 1024) {  // pixtab (premul) + folded BN
    int g = t / 9, tap = t - (t / 9) * 9;
    int kh = tap / 3, kw = tap - kh * 3;
    int h = kh * 5 + g / 5, w = kw * 5 + (g - (g / 5) * 5);
    pixtab[t] = (h < 9 && w < 9) ? (unsigned short)((h * 9 + w) * PITCH)
                                 : (unsigned short)(ZROW * PITCH);
    float inv = gamma[t] * rsqrtf(var[t] + 1e-5f);
    bnf[t] = make_float2(inv, beta[t] - mean[t] * inv);
  }

  // hoisted phase-1b weights: chv fixed per thread -> registers
  const int chv = tid & 127;
  float wv_e[9], wv_o[9];
#pragma unroll
  for (int t = 0; t < 9; ++t) {
    wv_e[t] = wv[(2 * chv) * 9 + t];
    wv_o[t] = wv[(2 * chv + 1) * 9 + t];
  }
  const float bv_e = bv[2 * chv], bv_o = bv[2 * chv + 1];

  // ---- phase 0c: pack + LDS write (single drain of the x loads)
#pragma unroll
  for (int rep = 0; rep < 10; ++rep) xTd[adr[rep]] = pack2(xe[rep], xo[rep]);
  if (tid < 128) xTd[adr[10]] = pack2(xe[10], xo[10]);

  __syncthreads();

  // ---- phase 1a: k1[p][ch] = sum_j x[p][ch+j-4]*wk[p][j] + bk[p]
  {
    auto k1fn = [&](int f) {
      int p = __builtin_amdgcn_readfirstlane(f >> 6);
      int u = f & 63;  // channel quad index
      const uint2* wrow2 = (const uint2*)(xTd + PITCHD * p);
      uint2 q0 = wrow2[u], q1 = wrow2[u + 1], q2 = wrow2[u + 2];
      float e[12] = {lo_f(q0.x), hi_f(q0.x), lo_f(q0.y), hi_f(q0.y),
                     lo_f(q1.x), hi_f(q1.x), lo_f(q1.y), hi_f(q1.y),
                     lo_f(q2.x), hi_f(q2.x), lo_f(q2.y), hi_f(q2.y)};
      const float* wkp = wk + p * 9;  // scalar loads (p uniform)
      float bkp = bk[p];
      float c0 = bkp, c1 = bkp, c2 = bkp, c3 = bkp;
#pragma unroll
      for (int j = 0; j < 9; ++j) {
        float wj = wkp[j];
        c0 = fmaf(wj, e[j], c0);
        c1 = fmaf(wj, e[j + 1], c1);
        c2 = fmaf(wj, e[j + 2], c2);
        c3 = fmaf(wj, e[j + 3], c3);
      }
      *(uint2*)(k1Td + PITCHD * p + 2 + 2 * u) =
          make_uint2(pack2(c0, c1), pack2(c2, c3));
    };
#pragma unroll
    for (int rep = 0; rep < 5; ++rep) k1fn(tid + rep * 1024);
    if (tid < 64) k1fn(5120 + tid);
  }

  // ---- phase 1b: v (3x3 depthwise) at the 18 pixels this half needs
  {
    auto vfn = [&](int f) {
      int e = __builtin_amdgcn_readfirstlane(f >> 7);  // 0..17 uniform
      int r0 = e / 6;
      int i = s * 3 + r0;  // v-pixel row 0..5
      int j = e - r0 * 6;  // v-pixel col 0..5
      float a_e = bv_e, a_o = bv_o;
#pragma unroll
      for (int di = 0; di < 3; ++di) {
        int ii = i + di - 1;
        if (ii < 0) continue;  // ii <= 6 < 9 always
#pragma unroll
        for (int dj = 0; dj < 3; ++dj) {
          int jj = j + dj - 1;
          if (jj < 0) continue;  // jj <= 6 < 9 always
          unsigned int d = xTd[PITCHD * (ii * 9 + jj) + 2 + chv];
          int t = di * 3 + dj;
          a_e = fmaf(lo_f(d), wv_e[t], a_e);
          a_o = fmaf(hi_f(d), wv_o[t], a_o);
        }
      }
      vTd[PITCHD * e + 2 + chv] = pack2(a_e, a_o);
    };
#pragma unroll
    for (int rep = 0; rep < 2; ++rep) vfn(tid + rep * 1024);
    if (tid < 256) vfn(2048 + tid);
  }
  if (tid < 180) {  // vT channel-pad zeros
    int e = tid / 10, k2 = tid - (tid / 10) * 10;
    vT[e * PITCH + ((k2 < 4) ? k2 : (256 + k2))] = 0;
  }
  __syncthreads();

  // ---- phase 2: 15 deduped instances; run TWICE (real + shadow probe)
  const int s4 = tid >> 8;  // slot 0..3 (wave-uniform)
  const int ch = tid & 255;
  const int ci0 = ch / 9;
  const int tap0 = ch - ci0 * 9;
  float* outb = out + ((size_t)b * C + ch) * HW;

  // per-lane gather walk is instance-invariant: hoist out of the k-loop
  int tq[9], cq[9];
  {
    int ci = ci0, tap = tap0;
#pragma unroll
    for (int q = 0; q < 9; ++q) {
      tq[q] = tap;
      cq[q] = 4 + ci;
      tap += 4;
      ci += 28;
      if (tap >= 9) { tap -= 9; ci += 1; }
    }
  }

#define PV_STORE(OH, OW)                                                   \
  do {                                                                     \
    int e_ = gh_i * 6 + ((OW)-3);                                          \
    const unsigned short* vrow_ = vT + e_ * PITCH;                         \
    float acc_ = 0.f;                                                      \
    _Pragma("unroll") for (int d_ = 0; d_ < 9; ++d_) acc_ =                \
        fmaf(a2[d_], bf2f(vrow_[ch + d_]), acc_);                          \
    acc_ *= inv_s;                                                         \
    if ((OH) < 6 && (OW) < 6)                                              \
      acc_ += bf2f(k1T[(((OH) + 3) * 9 + ((OW) + 3)) * PITCH + 4 + ch]);   \
    if (do_store) outb[(OH)*9 + (OW)] = acc_;                              \
    else asm volatile("" ::"v"(acc_));                                     \
  } while (0)

#pragma unroll
  for (int k = 0; k < 8; ++k) {
    const int inst = k & 3;       // k=4..7 shadow k=0..3
    const bool shadow = (k >= 4);
    if (shadow)  // force genuine re-reads + recompute (no CSE with real pass)
      asm volatile("" ::: "memory");
    int idx = s4 * 4 + inst;
    const bool do_store = (idx < 15) && !shadow;
    if (idx >= 15) idx = 14;  // dummy recomputes a real instance, no store
    int gh_i = idx / 5, gw_i = idx - (idx / 5) * 5;
    int oh = (s ? 6 : 3) + gh_i;
    int gh = s ? ((gh_i + 4) % 5) : (gh_i + 1);
    int g9 = __builtin_amdgcn_readfirstlane((gh * 5 + gw_i) * 9);

    // kq gather via premultiplied pixtab (zero-row kills validity selects)
    float kq[18];
#pragma unroll
    for (int q = 0; q < 9; ++q) {
      int off = (int)pixtab[g9 + tq[q]] + cq[q];
      kq[q] = bf2f(xT[off]);
      kq[9 + q] = bf2f(k1T[off]);
    }

    __builtin_amdgcn_s_setprio(1);
    // w1 -> folded BN -> ReLU
    float r[9];
#pragma unroll
    for (int o = 0; o < 9; ++o) {
      int m = g9 + o;
      const float* w1m = w1 + m * 18;
      float a = 0.f;
#pragma unroll
      for (int i2 = 0; i2 < 18; ++i2) a = fmaf(w1m[i2], kq[i2], a);
      float2 bn = bnf[m];
      a = fmaf(a, bn.x, bn.y);
      r[o] = fmaxf(a, 0.f);
    }

    // w2 + b2 -> softmax (registers)
    float a2[9], mx = -1e30f;
#pragma unroll
    for (int d = 0; d < 9; ++d) {
      int m = g9 + d;
      const float* w2m = w2 + m * 9;
      float a = b2[m];
#pragma unroll
      for (int o = 0; o < 9; ++o) a = fmaf(w2m[o], r[o], a);
      a2[d] = a;
      mx = fmaxf(mx, a);
    }
    float ssum = 0.f;
#pragma unroll
    for (int d = 0; d < 9; ++d) {
      a2[d] = __expf(a2[d] - mx);
      ssum += a2[d];
    }
    float inv_s = __builtin_amdgcn_rcpf(ssum);
    __builtin_amdgcn_s_setprio(0);

    // PV + k1-add + store; gw==1 serves both ow=3 and ow=8
    int ow0 = (gw_i == 0) ? 7 : (gw_i + 2);
    PV_STORE(oh, ow0);
    if (gw_i == 1) PV_STORE(oh, 8);
  }
#undef PV_STORE

  // ---- epilogue: non-PV output pixels
  if (s == 0) {
    if (s4 < 3) {
      int oh = s4;  // rows 0..2: k1 where ow<6, else 0
#pragma unroll
      for (int ow = 0; ow < 9; ++ow) {
        float v2 = 0.f;
        if (ow < 6)
          v2 = bf2f(k1T[((oh + 3) * 9 + (ow + 3)) * PITCH + 4 + ch]);
        outb[oh * 9 + ow] = v2;
      }
    } else {
      // rows 3..5, cols 0..2: k1-only
#pragma unroll
      for (int r0 = 0; r0 < 3; ++r0) {
        int oh = 3 + r0;
#pragma unroll
        for (int ow = 0; ow < 3; ++ow)
          outb[oh * 9 + ow] =
              bf2f(k1T[((oh + 3) * 9 + (ow + 3)) * PITCH + 4 + ch]);
      }
    }
  } else if (s4 < 3) {
    int oh = 6 + s4;  // rows 6..8, cols 0..2: zero
    outb[oh * 9 + 0] = 0.f;
    outb[oh * 9 + 1] = 0.f;
    outb[oh * 9 + 2] = 0.f;
  }
}

extern "C" void kernel_launch(void* const* d_in, const int* in_sizes, int n_in,
                              void* d_out, int out_size, void* d_ws, size_t ws_size,
                              hipStream_t stream) {
  const float* x     = (const float*)d_in[0];
  const float* wk    = (const float*)d_in[1];
  const float* bk    = (const float*)d_in[2];
  const float* w1    = (const float*)d_in[3];
  const float* gamma = (const float*)d_in[4];
  const float* beta  = (const float*)d_in[5];
  const float* mean  = (const float*)d_in[6];
  const float* var   = (const float*)d_in[7];
  const float* w2    = (const float*)d_in[8];
  const float* b2    = (const float*)d_in[9];
  const float* wv    = (const float*)d_in[10];
  const float* bv    = (const float*)d_in[11];
  float* out = (float*)d_out;

  hipLaunchKernelGGL(semca_fused, dim3(256), dim3(1024), 0, stream,
                     x, wk, bk, w1, gamma, beta, mean, var, w2, b2, wv, bv, out);
}

// Round 7
// 28.306 us; speedup vs baseline: 1.3427x; 1.3427x over previous
//
#include <hip/hip_runtime.h>

#define C 256
#define HW 81
#define PITCH 292   // ushorts per pixel row: [4 pad][256 ch][32 pad] (even dword pitch)
#define PITCHD 146  // dwords per pixel row; 146%32=18 -> gather tap bases ~4-apart
#define ZROW 81     // zeroed row index for invalid gather taps

typedef float f32x4 __attribute__((ext_vector_type(4), aligned(4)));
typedef float f32x3 __attribute__((ext_vector_type(3), aligned(4)));

__device__ __forceinline__ float lo_f(unsigned int d) {
  union { unsigned int i; float f; } c; c.i = d << 16; return c.f;
}
__device__ __forceinline__ float hi_f(unsigned int d) {
  union { unsigned int i; float f; } c; c.i = d & 0xffff0000u; return c.f;
}
__device__ __forceinline__ float bf2f(unsigned short u) {
  union { unsigned int i; float f; } c; c.i = ((unsigned int)u) << 16; return c.f;
}
__device__ __forceinline__ unsigned short f2bf(float f) {
  union { float f; unsigned int i; } c; c.f = f;
  return (unsigned short)((c.i + 0x7fffu + ((c.i >> 16) & 1u)) >> 16);
}
__device__ __forceinline__ unsigned int pack2(float a, float b) {
  return (unsigned int)f2bf(a) | ((unsigned int)f2bf(b) << 16);
}

// ---------------------------------------------------------------------------
// Fully fused SeMCA. Block = (b, s): s=0 -> output rows 0..5, s=1 -> rows 6..8.
// 1024 threads = 4 instance-slots x 256 channels. 2 barriers.
// R7 (theory from R6 probe: exposed store-issue + gather-address overheads;
// no pipe near roofline, VALUBusy 54%):
//  - epilogue stores vectorized: per-thread-contiguous rows written as
//    dwordx4/x3 (CDNA global stores need only 4B alignment) -> s=0 threads
//    drop 9 epilogue store instrs to 3, s=1 drops 3 to 1. Each scattered
//    wave-store costs ~64 TA cycles, so this cuts ~2.5us of store-pipe time.
//  - all 36 gather offsets (pixtab[g9+tq]+cq) preloaded into registers
//    before the instance loop (cross-instance hoist the compiler can't
//    prove; removes pixtab read+add from each instance's critical path).
//  - phases 0/1 byte-identical to R5 (27.61us base).
// ---------------------------------------------------------------------------
__global__ __launch_bounds__(1024) void semca_fused(
    const float* __restrict__ x, const float* __restrict__ wk,
    const float* __restrict__ bk, const float* __restrict__ w1,
    const float* __restrict__ gamma, const float* __restrict__ beta,
    const float* __restrict__ mean, const float* __restrict__ var,
    const float* __restrict__ w2, const float* __restrict__ b2,
    const float* __restrict__ wv, const float* __restrict__ bv,
    float* __restrict__ out) {
  __shared__ unsigned short xT[82 * PITCH];   // 47,888 B (row 81 = zeros)
  __shared__ unsigned short k1T[82 * PITCH];  // 47,888 B (row 81 = zeros)
  __shared__ unsigned short vT[18 * PITCH];   // 10,512 B
  __shared__ unsigned short pixtab[228];      //    456 B (premultiplied by PITCH)
  __shared__ float2 bnf[225];                 //  1,800 B  (~106 KiB total)

  const int blk = blockIdx.x;
  const int b = (blk & 7) * 16 + ((blk >> 3) & 15);  // XCD-paired, bijective
  const int s = blk >> 7;
  const int tid = threadIdx.x;
  const float* xb = x + (size_t)b * (C * HW);

  unsigned int* xTd = (unsigned int*)xT;
  unsigned int* k1Td = (unsigned int*)k1T;
  unsigned int* vTd = (unsigned int*)vT;

  // ---- phase 0a: issue ALL x loads first (registers), incremental walk
  float xe[11], xo[11];
  int adr[11];
  {
    int chp = tid / HW;            // single division
    int p = tid - chp * HW;
#pragma unroll
    for (int rep = 0; rep < 10; ++rep) {
      const float* base = xb + (2 * chp) * HW + p;
      xe[rep] = base[0];
      xo[rep] = base[HW];
      adr[rep] = PITCHD * p + 2 + chp;
      chp += 12;                   // advance f by 1024 = 12*81 + 52
      p += 52;
      if (p >= HW) { p -= HW; chp += 1; }
    }
    if (tid < 128) {               // tail item f = 10240 + tid
      int f = 10240 + tid;
      int c2 = f / HW, p2 = f - c2 * HW;
      xe[10] = xb[2 * c2 * HW + p2];
      xo[10] = xb[(2 * c2 + 1) * HW + p2];
      adr[10] = PITCHD * p2 + 2 + c2;
    }
  }

  // ---- phase 0b: independent work under the load shadow
  for (int t = tid; t < 810; t += 1024) {  // x channel-pad zeros
    int p = t / 10, k2 = t - (t / 10) * 10;
    xT[p * PITCH + ((k2 < 4) ? k2 : (256 + k2))] = 0;
  }
  if (tid < PITCHD) {                      // zero row 81 of xT and k1T
    xTd[PITCHD * ZROW + tid] = 0;
    k1Td[PITCHD * ZROW + tid] = 0;
  }
  for (int t = tid; t < 225; t += 1024) {  // pixtab (premul) + folded BN
    int g = t / 9, tap = t - (t / 9) * 9;
    int kh = tap / 3, kw = tap - kh * 3;
    int h = kh * 5 + g / 5, w = kw * 5 + (g - (g / 5) * 5);
    pixtab[t] = (h < 9 && w < 9) ? (unsigned short)((h * 9 + w) * PITCH)
                                 : (unsigned short)(ZROW * PITCH);
    float inv = gamma[t] * rsqrtf(var[t] + 1e-5f);
    bnf[t] = make_float2(inv, beta[t] - mean[t] * inv);
  }

  // hoisted phase-1b weights: chv fixed per thread -> registers
  const int chv = tid & 127;
  float wv_e[9], wv_o[9];
#pragma unroll
  for (int t = 0; t < 9; ++t) {
    wv_e[t] = wv[(2 * chv) * 9 + t];
    wv_o[t] = wv[(2 * chv + 1) * 9 + t];
  }
  const float bv_e = bv[2 * chv], bv_o = bv[2 * chv + 1];

  // ---- phase 0c: pack + LDS write (single drain of the x loads)
#pragma unroll
  for (int rep = 0; rep < 10; ++rep) xTd[adr[rep]] = pack2(xe[rep], xo[rep]);
  if (tid < 128) xTd[adr[10]] = pack2(xe[10], xo[10]);

  __syncthreads();

  // ---- phase 1a: k1[p][ch] = sum_j x[p][ch+j-4]*wk[p][j] + bk[p]
  {
    auto k1fn = [&](int f) {
      int p = __builtin_amdgcn_readfirstlane(f >> 6);
      int u = f & 63;  // channel quad index
      const uint2* wrow2 = (const uint2*)(xTd + PITCHD * p);
      uint2 q0 = wrow2[u], q1 = wrow2[u + 1], q2 = wrow2[u + 2];
      float e[12] = {lo_f(q0.x), hi_f(q0.x), lo_f(q0.y), hi_f(q0.y),
                     lo_f(q1.x), hi_f(q1.x), lo_f(q1.y), hi_f(q1.y),
                     lo_f(q2.x), hi_f(q2.x), lo_f(q2.y), hi_f(q2.y)};
      const float* wkp = wk + p * 9;  // scalar loads (p uniform)
      float bkp = bk[p];
      float c0 = bkp, c1 = bkp, c2 = bkp, c3 = bkp;
#pragma unroll
      for (int j = 0; j < 9; ++j) {
        float wj = wkp[j];
        c0 = fmaf(wj, e[j], c0);
        c1 = fmaf(wj, e[j + 1], c1);
        c2 = fmaf(wj, e[j + 2], c2);
        c3 = fmaf(wj, e[j + 3], c3);
      }
      *(uint2*)(k1Td + PITCHD * p + 2 + 2 * u) =
          make_uint2(pack2(c0, c1), pack2(c2, c3));
    };
#pragma unroll
    for (int rep = 0; rep < 5; ++rep) k1fn(tid + rep * 1024);
    if (tid < 64) k1fn(5120 + tid);
  }

  // ---- phase 1b: v (3x3 depthwise) at the 18 pixels this half needs
  {
    auto vfn = [&](int f) {
      int e = __builtin_amdgcn_readfirstlane(f >> 7);  // 0..17 uniform
      int r0 = e / 6;
      int i = s * 3 + r0;  // v-pixel row 0..5
      int j = e - r0 * 6;  // v-pixel col 0..5
      float a_e = bv_e, a_o = bv_o;
#pragma unroll
      for (int di = 0; di < 3; ++di) {
        int ii = i + di - 1;
        if (ii < 0) continue;  // ii <= 6 < 9 always
#pragma unroll
        for (int dj = 0; dj < 3; ++dj) {
          int jj = j + dj - 1;
          if (jj < 0) continue;  // jj <= 6 < 9 always
          unsigned int d = xTd[PITCHD * (ii * 9 + jj) + 2 + chv];
          int t = di * 3 + dj;
          a_e = fmaf(lo_f(d), wv_e[t], a_e);
          a_o = fmaf(hi_f(d), wv_o[t], a_o);
        }
      }
      vTd[PITCHD * e + 2 + chv] = pack2(a_e, a_o);
    };
#pragma unroll
    for (int rep = 0; rep < 2; ++rep) vfn(tid + rep * 1024);
    if (tid < 256) vfn(2048 + tid);
  }
  if (tid < 180) {  // vT channel-pad zeros
    int e = tid / 10, k2 = tid - (tid / 10) * 10;
    vT[e * PITCH + ((k2 < 4) ? k2 : (256 + k2))] = 0;
  }
  __syncthreads();

  // ---- phase 2: 15 deduped instances; 4 slots x 4 unrolled iterations
  const int s4 = tid >> 8;  // slot 0..3 (wave-uniform)
  const int ch = tid & 255;
  const int ci0 = ch / 9;
  const int tap0 = ch - ci0 * 9;
  float* outb = out + ((size_t)b * C + ch) * HW;

  // per-lane gather walk is instance-invariant: hoist out of the k-loop
  int tq[9], cq[9];
  {
    int ci = ci0, tap = tap0;
#pragma unroll
    for (int q = 0; q < 9; ++q) {
      tq[q] = tap;
      cq[q] = 4 + ci;
      tap += 4;
      ci += 28;
      if (tap >= 9) { tap -= 9; ci += 1; }
    }
  }

  // instance parameters + ALL 36 gather offsets preloaded (pixtab hoist)
  int g9s[4], ohs[4], ghis[4], gwis[4];
  bool valids[4];
  int offs[4][9];
#pragma unroll
  for (int k = 0; k < 4; ++k) {
    int idx = s4 * 4 + k;
    valids[k] = (idx < 15);
    if (idx >= 15) idx = 14;  // dummy recomputes a real instance, no store
    int gh_i = idx / 5, gw_i = idx - (idx / 5) * 5;
    ghis[k] = gh_i;
    gwis[k] = gw_i;
    ohs[k] = (s ? 6 : 3) + gh_i;
    int gh = s ? ((gh_i + 4) % 5) : (gh_i + 1);
    int g9 = __builtin_amdgcn_readfirstlane((gh * 5 + gw_i) * 9);
    g9s[k] = g9;
#pragma unroll
    for (int q = 0; q < 9; ++q) offs[k][q] = (int)pixtab[g9 + tq[q]] + cq[q];
  }

#define PV_STORE(OH, OW)                                                   \
  do {                                                                     \
    int e_ = gh_i * 6 + ((OW)-3);                                          \
    const unsigned short* vrow_ = vT + e_ * PITCH;                         \
    float acc_ = 0.f;                                                      \
    _Pragma("unroll") for (int d_ = 0; d_ < 9; ++d_) acc_ =                \
        fmaf(a2[d_], bf2f(vrow_[ch + d_]), acc_);                          \
    acc_ *= inv_s;                                                         \
    if ((OH) < 6 && (OW) < 6)                                              \
      acc_ += bf2f(k1T[(((OH) + 3) * 9 + ((OW) + 3)) * PITCH + 4 + ch]);   \
    if (valid_inst) outb[(OH)*9 + (OW)] = acc_;                            \
  } while (0)

#pragma unroll
  for (int k = 0; k < 4; ++k) {
    const bool valid_inst = valids[k];
    const int g9 = g9s[k];
    const int gh_i = ghis[k], gw_i = gwis[k], oh = ohs[k];

    // kq gather: offsets precomputed (zero-row kills validity selects)
    float kq[18];
#pragma unroll
    for (int q = 0; q < 9; ++q) {
      kq[q] = bf2f(xT[offs[k][q]]);
      kq[9 + q] = bf2f(k1T[offs[k][q]]);
    }

    __builtin_amdgcn_s_setprio(1);
    // w1 -> folded BN -> ReLU
    float r[9];
#pragma unroll
    for (int o = 0; o < 9; ++o) {
      int m = g9 + o;
      const float* w1m = w1 + m * 18;
      float a = 0.f;
#pragma unroll
      for (int i2 = 0; i2 < 18; ++i2) a = fmaf(w1m[i2], kq[i2], a);
      float2 bn = bnf[m];
      a = fmaf(a, bn.x, bn.y);
      r[o] = fmaxf(a, 0.f);
    }

    // w2 + b2 -> softmax (registers)
    float a2[9], mx = -1e30f;
#pragma unroll
    for (int d = 0; d < 9; ++d) {
      int m = g9 + d;
      const float* w2m = w2 + m * 9;
      float a = b2[m];
#pragma unroll
      for (int o = 0; o < 9; ++o) a = fmaf(w2m[o], r[o], a);
      a2[d] = a;
      mx = fmaxf(mx, a);
    }
    float ssum = 0.f;
#pragma unroll
    for (int d = 0; d < 9; ++d) {
      a2[d] = __expf(a2[d] - mx);
      ssum += a2[d];
    }
    float inv_s = __builtin_amdgcn_rcpf(ssum);
    __builtin_amdgcn_s_setprio(0);

    // PV + k1-add + store; gw==1 serves both ow=3 and ow=8
    int ow0 = (gw_i == 0) ? 7 : (gw_i + 2);
    PV_STORE(oh, ow0);
    if (gw_i == 1) PV_STORE(oh, 8);
  }
#undef PV_STORE

  // ---- epilogue: non-PV output pixels, WIDE stores (4B-aligned vec types)
  if (s == 0) {
    if (s4 < 3) {
      int oh = s4;  // rows 0..2: k1 where ow<6, else 0; 9 floats contiguous
      float v[9];
#pragma unroll
      for (int ow = 0; ow < 9; ++ow) {
        v[ow] = (ow < 6)
                    ? bf2f(k1T[((oh + 3) * 9 + (ow + 3)) * PITCH + 4 + ch])
                    : 0.f;
      }
      *(f32x4*)(outb + oh * 9) = (f32x4){v[0], v[1], v[2], v[3]};
      *(f32x4*)(outb + oh * 9 + 4) = (f32x4){v[4], v[5], v[6], v[7]};
      outb[oh * 9 + 8] = v[8];
    } else {
      // rows 3..5, cols 0..2: k1-only; 3 contiguous floats per row
#pragma unroll
      for (int r0 = 0; r0 < 3; ++r0) {
        int oh = 3 + r0;
        f32x3 v;
#pragma unroll
        for (int ow = 0; ow < 3; ++ow)
          v[ow] = bf2f(k1T[((oh + 3) * 9 + (ow + 3)) * PITCH + 4 + ch]);
        *(f32x3*)(outb + oh * 9) = v;
      }
    }
  } else if (s4 < 3) {
    int oh = 6 + s4;  // rows 6..8, cols 0..2: zero
    *(f32x3*)(outb + oh * 9) = (f32x3){0.f, 0.f, 0.f};
  }
}

extern "C" void kernel_launch(void* const* d_in, const int* in_sizes, int n_in,
                              void* d_out, int out_size, void* d_ws, size_t ws_size,
                              hipStream_t stream) {
  const float* x     = (const float*)d_in[0];
  const float* wk    = (const float*)d_in[1];
  const float* bk    = (const float*)d_in[2];
  const float* w1    = (const float*)d_in[3];
  const float* gamma = (const float*)d_in[4];
  const float* beta  = (const float*)d_in[5];
  const float* mean  = (const float*)d_in[6];
  const float* var   = (const float*)d_in[7];
  const float* w2    = (const float*)d_in[8];
  const float* b2    = (const float*)d_in[9];
  const float* wv    = (const float*)d_in[10];
  const float* bv    = (const float*)d_in[11];
  float* out = (float*)d_out;

  hipLaunchKernelGGL(semca_fused, dim3(256), dim3(1024), 0, stream,
                     x, wk, bk, w1, gamma, beta, mean, var, w2, b2, wv, bv, out);
}

// Round 9
// 25.981 us; speedup vs baseline: 1.4628x; 1.0895x over previous
//
#include <hip/hip_runtime.h>

#define C 256
#define HW 81
#define PITCH 292   // ushorts per pixel row: [4 pad][256 ch][32 pad] (even dword pitch)
#define PITCHD 146  // dwords per pixel row; 146%32=18 -> gather tap bases ~4-apart
#define ZROW 81     // zeroed row index for invalid gather taps

typedef __fp16 h2 __attribute__((ext_vector_type(2)));  // matches builtin V2h

__device__ __forceinline__ float us2f(unsigned short u) {  // f16 bits -> f32
  union { unsigned short s; __fp16 h; } c; c.s = u; return (float)c.h;
}
__device__ __forceinline__ float lo_h(unsigned int d) {
  union { unsigned int i; h2 h; } c; c.i = d; return (float)c.h.x;
}
__device__ __forceinline__ float hi_h(unsigned int d) {
  union { unsigned int i; h2 h; } c; c.i = d; return (float)c.h.y;
}
__device__ __forceinline__ unsigned int pkh2(float a, float b) {  // 1x cvt_pkrtz
  union { h2 h; unsigned int i; } c;
  c.h = __builtin_amdgcn_cvt_pkrtz(a, b);
  return c.i;
}
__device__ __forceinline__ h2 as_h2(unsigned int d) {
  union { unsigned int i; h2 h; } c; c.i = d; return c.h;
}
__device__ __forceinline__ float dot2(unsigned int a, unsigned int b, float c) {
#if __has_builtin(__builtin_amdgcn_fdot2)
  return __builtin_amdgcn_fdot2(as_h2(a), as_h2(b), c, false);
#else
  h2 x = as_h2(a), y = as_h2(b);
  return fmaf((float)x.y, (float)y.y, fmaf((float)x.x, (float)y.x, c));
#endif
}

// ---------------------------------------------------------------------------
// Fully fused SeMCA. Block = (b, s): s=0 -> output rows 0..5, s=1 -> rows 6..8.
// 1024 threads = 4 instance-slots x 256 channels. 2 barriers.
// R9 = R8 with the h2 type fixed to __fp16 ext_vector(2) (cvt_pkrtz/fdot2
// builtin signature). Theory under test (from R6 probe): margin is
// instruction-issue-bound; real cuts vs R5 (27.61us):
//  - xT/k1T/vT store f16 (MORE precise than bf16; cvt_pkrtz = 1 op vs 3).
//  - w1 pre-packed as half2 (w1[m][q],w1[m][9+q]) -> 81 v_dot2_f32_f16
//    replaces 162 FMA; gathered (x,k1) pair packs to one half2 via lshl_or.
//  - w2 pre-packed o-pairs -> 36 fdot2 + 9 FMA replaces 81 FMA.
//  - LDS +14.4 KiB tables (~121 KiB total, still 1 block/CU).
// ---------------------------------------------------------------------------
__global__ __launch_bounds__(1024) void semca_fused(
    const float* __restrict__ x, const float* __restrict__ wk,
    const float* __restrict__ bk, const float* __restrict__ w1,
    const float* __restrict__ gamma, const float* __restrict__ beta,
    const float* __restrict__ mean, const float* __restrict__ var,
    const float* __restrict__ w2, const float* __restrict__ b2,
    const float* __restrict__ wv, const float* __restrict__ bv,
    float* __restrict__ out) {
  __shared__ unsigned short xT[82 * PITCH];   // 47,888 B (row 81 = zeros), f16
  __shared__ unsigned short k1T[82 * PITCH];  // 47,888 B (row 81 = zeros), f16
  __shared__ unsigned short vT[18 * PITCH];   // 10,512 B, f16
  __shared__ unsigned short pixtab[228];      //    456 B (premultiplied by PITCH)
  __shared__ float2 bnf[225];                 //  1,800 B
  __shared__ unsigned int w1p[225 * 12];      // 10,800 B half2 pairs, 48B/row
  __shared__ unsigned int w2p[225 * 4];       //  3,600 B half2 o-pairs (16B/row)

  const int blk = blockIdx.x;
  const int b = (blk & 7) * 16 + ((blk >> 3) & 15);  // XCD-paired, bijective
  const int s = blk >> 7;
  const int tid = threadIdx.x;
  const float* xb = x + (size_t)b * (C * HW);

  unsigned int* xTd = (unsigned int*)xT;
  unsigned int* k1Td = (unsigned int*)k1T;
  unsigned int* vTd = (unsigned int*)vT;

  // ---- phase 0a: issue ALL x loads first (registers), incremental walk
  float xe[11], xo[11];
  int adr[11];
  {
    int chp = tid / HW;            // single division
    int p = tid - chp * HW;
#pragma unroll
    for (int rep = 0; rep < 10; ++rep) {
      const float* base = xb + (2 * chp) * HW + p;
      xe[rep] = base[0];
      xo[rep] = base[HW];
      adr[rep] = PITCHD * p + 2 + chp;
      chp += 12;                   // advance f by 1024 = 12*81 + 52
      p += 52;
      if (p >= HW) { p -= HW; chp += 1; }
    }
    if (tid < 128) {               // tail item f = 10240 + tid
      int f = 10240 + tid;
      int c2 = f / HW, p2 = f - c2 * HW;
      xe[10] = xb[2 * c2 * HW + p2];
      xo[10] = xb[(2 * c2 + 1) * HW + p2];
      adr[10] = PITCHD * p2 + 2 + c2;
    }
  }

  // ---- phase 0b: independent work under the load shadow
  for (int t = tid; t < 810; t += 1024) {  // x channel-pad zeros
    int p = t / 10, k2 = t - (t / 10) * 10;
    xT[p * PITCH + ((k2 < 4) ? k2 : (256 + k2))] = 0;
  }
  if (tid < PITCHD) {                      // zero row 81 of xT and k1T
    xTd[PITCHD * ZROW + tid] = 0;
    k1Td[PITCHD * ZROW + tid] = 0;
  }
  for (int t = tid; t < 225; t += 1024) {  // pixtab (premul) + folded BN
    int g = t / 9, tap = t - (t / 9) * 9;
    int kh = tap / 3, kw = tap - kh * 3;
    int h = kh * 5 + g / 5, w = kw * 5 + (g - (g / 5) * 5);
    pixtab[t] = (h < 9 && w < 9) ? (unsigned short)((h * 9 + w) * PITCH)
                                 : (unsigned short)(ZROW * PITCH);
    float inv = gamma[t] * rsqrtf(var[t] + 1e-5f);
    bnf[t] = make_float2(inv, beta[t] - mean[t] * inv);
  }
  for (int t = tid; t < 2025; t += 1024) {  // w1 packed pairs (x-tap, k1-tap)
    int m = t / 9, q = t - m * 9;
    w1p[m * 12 + q] = pkh2(w1[m * 18 + q], w1[m * 18 + 9 + q]);
  }
  if (tid < 900) {                          // w2 packed o-pairs (o=0..7)
    int m = tid >> 2, j = tid & 3;
    w2p[m * 4 + j] = pkh2(w2[m * 9 + 2 * j], w2[m * 9 + 2 * j + 1]);
  }

  // hoisted phase-1b weights: chv fixed per thread -> registers
  const int chv = tid & 127;
  float wv_e[9], wv_o[9];
#pragma unroll
  for (int t = 0; t < 9; ++t) {
    wv_e[t] = wv[(2 * chv) * 9 + t];
    wv_o[t] = wv[(2 * chv + 1) * 9 + t];
  }
  const float bv_e = bv[2 * chv], bv_o = bv[2 * chv + 1];

  // ---- phase 0c: pack (f16) + LDS write (single drain of the x loads)
#pragma unroll
  for (int rep = 0; rep < 10; ++rep) xTd[adr[rep]] = pkh2(xe[rep], xo[rep]);
  if (tid < 128) xTd[adr[10]] = pkh2(xe[10], xo[10]);

  __syncthreads();

  // ---- phase 1a: k1[p][ch] = sum_j x[p][ch+j-4]*wk[p][j] + bk[p]
  // width-4: ushorts 4u..4u+11 (ch-4 halo via left pad) = dwords 2u..2u+5
  // from the ROW BASE -> 3x ds_read_b64, 1x b64 write (f16).
  {
    auto k1fn = [&](int f) {
      int p = __builtin_amdgcn_readfirstlane(f >> 6);
      int u = f & 63;  // channel quad index
      const uint2* wrow2 = (const uint2*)(xTd + PITCHD * p);
      uint2 q0 = wrow2[u], q1 = wrow2[u + 1], q2 = wrow2[u + 2];
      float e[12] = {lo_h(q0.x), hi_h(q0.x), lo_h(q0.y), hi_h(q0.y),
                     lo_h(q1.x), hi_h(q1.x), lo_h(q1.y), hi_h(q1.y),
                     lo_h(q2.x), hi_h(q2.x), lo_h(q2.y), hi_h(q2.y)};
      const float* wkp = wk + p * 9;  // scalar loads (p uniform)
      float bkp = bk[p];
      float c0 = bkp, c1 = bkp, c2 = bkp, c3 = bkp;
#pragma unroll
      for (int j = 0; j < 9; ++j) {
        float wj = wkp[j];
        c0 = fmaf(wj, e[j], c0);
        c1 = fmaf(wj, e[j + 1], c1);
        c2 = fmaf(wj, e[j + 2], c2);
        c3 = fmaf(wj, e[j + 3], c3);
      }
      *(uint2*)(k1Td + PITCHD * p + 2 + 2 * u) =
          make_uint2(pkh2(c0, c1), pkh2(c2, c3));
    };
#pragma unroll
    for (int rep = 0; rep < 5; ++rep) k1fn(tid + rep * 1024);
    if (tid < 64) k1fn(5120 + tid);
  }

  // ---- phase 1b: v (3x3 depthwise) at the 18 pixels this half needs
  {
    auto vfn = [&](int f) {
      int e = __builtin_amdgcn_readfirstlane(f >> 7);  // 0..17 uniform
      int r0 = e / 6;
      int i = s * 3 + r0;  // v-pixel row 0..5
      int j = e - r0 * 6;  // v-pixel col 0..5
      float a_e = bv_e, a_o = bv_o;
#pragma unroll
      for (int di = 0; di < 3; ++di) {
        int ii = i + di - 1;
        if (ii < 0) continue;  // ii <= 6 < 9 always
#pragma unroll
        for (int dj = 0; dj < 3; ++dj) {
          int jj = j + dj - 1;
          if (jj < 0) continue;  // jj <= 6 < 9 always
          unsigned int d = xTd[PITCHD * (ii * 9 + jj) + 2 + chv];
          int t = di * 3 + dj;
          a_e = fmaf(lo_h(d), wv_e[t], a_e);
          a_o = fmaf(hi_h(d), wv_o[t], a_o);
        }
      }
      vTd[PITCHD * e + 2 + chv] = pkh2(a_e, a_o);
    };
#pragma unroll
    for (int rep = 0; rep < 2; ++rep) vfn(tid + rep * 1024);
    if (tid < 256) vfn(2048 + tid);
  }
  if (tid < 180) {  // vT channel-pad zeros
    int e = tid / 10, k2 = tid - (tid / 10) * 10;
    vT[e * PITCH + ((k2 < 4) ? k2 : (256 + k2))] = 0;
  }
  __syncthreads();

  // ---- phase 2: 15 deduped instances; 4 slots x 4 unrolled iterations
  const int s4 = tid >> 8;  // slot 0..3 (wave-uniform)
  const int ch = tid & 255;
  const int ci0 = ch / 9;
  const int tap0 = ch - ci0 * 9;
  float* outb = out + ((size_t)b * C + ch) * HW;

  // per-lane gather walk is instance-invariant
  int tq[9], cq[9];
  {
    int ci = ci0, tap = tap0;
#pragma unroll
    for (int q = 0; q < 9; ++q) {
      tq[q] = tap;
      cq[q] = 4 + ci;
      tap += 4;
      ci += 28;
      if (tap >= 9) { tap -= 9; ci += 1; }
    }
  }

#define PV_STORE(OH, OW)                                                   \
  do {                                                                     \
    int e_ = gh_i * 6 + ((OW)-3);                                          \
    const unsigned short* vrow_ = vT + e_ * PITCH;                         \
    float acc_ = 0.f;                                                      \
    _Pragma("unroll") for (int d_ = 0; d_ < 9; ++d_) acc_ =                \
        fmaf(a2[d_], us2f(vrow_[ch + d_]), acc_);                          \
    acc_ *= inv_s;                                                         \
    if ((OH) < 6 && (OW) < 6)                                              \
      acc_ += us2f(k1T[(((OH) + 3) * 9 + ((OW) + 3)) * PITCH + 4 + ch]);   \
    if (valid_inst) outb[(OH)*9 + (OW)] = acc_;                            \
  } while (0)

#pragma unroll
  for (int k = 0; k < 4; ++k) {
    int idx = s4 * 4 + k;
    const bool valid_inst = (idx < 15);
    if (!valid_inst) idx = 14;  // dummy recomputes a real instance, no store
    int gh_i = idx / 5, gw_i = idx - (idx / 5) * 5;
    int oh = (s ? 6 : 3) + gh_i;
    int gh = s ? ((gh_i + 4) % 5) : (gh_i + 1);
    int g9 = __builtin_amdgcn_readfirstlane((gh * 5 + gw_i) * 9);

    // kq gather -> packed half2 (x_q, k1_q): 2 u16 reads + 1 lshl_or per q
    unsigned int kqp[9];
#pragma unroll
    for (int q = 0; q < 9; ++q) {
      int off = (int)pixtab[g9 + tq[q]] + cq[q];
      unsigned int xv = xT[off], kv = k1T[off];
      kqp[q] = xv | (kv << 16);
    }

    __builtin_amdgcn_s_setprio(1);
    // w1 (packed pairs, fdot2) -> folded BN -> ReLU
    float r[9];
#pragma unroll
    for (int o = 0; o < 9; ++o) {
      int m = g9 + o;
      const unsigned int* wp = w1p + m * 12;
      float a = 0.f;
#pragma unroll
      for (int q = 0; q < 9; ++q) a = dot2(kqp[q], wp[q], a);
      float2 bn = bnf[m];
      a = fmaf(a, bn.x, bn.y);
      r[o] = fmaxf(a, 0.f);
    }

    // w2 (packed o-pairs, fdot2) + b2 -> softmax (registers)
    unsigned int rp[4];
#pragma unroll
    for (int j = 0; j < 4; ++j) rp[j] = pkh2(r[2 * j], r[2 * j + 1]);
    float a2[9], mx = -1e30f;
#pragma unroll
    for (int d = 0; d < 9; ++d) {
      int m = g9 + d;
      const unsigned int* wq = w2p + m * 4;
      float a = b2[m];
#pragma unroll
      for (int j = 0; j < 4; ++j) a = dot2(rp[j], wq[j], a);
      a = fmaf(w2[m * 9 + 8], r[8], a);
      a2[d] = a;
      mx = fmaxf(mx, a);
    }
    float ssum = 0.f;
#pragma unroll
    for (int d = 0; d < 9; ++d) {
      a2[d] = __expf(a2[d] - mx);
      ssum += a2[d];
    }
    float inv_s = __builtin_amdgcn_rcpf(ssum);
    __builtin_amdgcn_s_setprio(0);

    // PV + k1-add + store; gw==1 serves both ow=3 and ow=8
    int ow0 = (gw_i == 0) ? 7 : (gw_i + 2);
    PV_STORE(oh, ow0);
    if (gw_i == 1) PV_STORE(oh, 8);
  }
#undef PV_STORE

  // ---- epilogue: non-PV output pixels
  if (s == 0) {
    if (s4 < 3) {
      int oh = s4;  // rows 0..2: k1 where ow<6, else 0
#pragma unroll
      for (int ow = 0; ow < 9; ++ow) {
        float v2 = 0.f;
        if (ow < 6)
          v2 = us2f(k1T[((oh + 3) * 9 + (ow + 3)) * PITCH + 4 + ch]);
        outb[oh * 9 + ow] = v2;
      }
    } else {
      // rows 3..5, cols 0..2: k1-only
#pragma unroll
      for (int r0 = 0; r0 < 3; ++r0) {
        int oh = 3 + r0;
#pragma unroll
        for (int ow = 0; ow < 3; ++ow)
          outb[oh * 9 + ow] =
              us2f(k1T[((oh + 3) * 9 + (ow + 3)) * PITCH + 4 + ch]);
      }
    }
  } else if (s4 < 3) {
    int oh = 6 + s4;  // rows 6..8, cols 0..2: zero
    outb[oh * 9 + 0] = 0.f;
    outb[oh * 9 + 1] = 0.f;
    outb[oh * 9 + 2] = 0.f;
  }
}

extern "C" void kernel_launch(void* const* d_in, const int* in_sizes, int n_in,
                              void* d_out, int out_size, void* d_ws, size_t ws_size,
                              hipStream_t stream) {
  const float* x     = (const float*)d_in[0];
  const float* wk    = (const float*)d_in[1];
  const float* bk    = (const float*)d_in[2];
  const float* w1    = (const float*)d_in[3];
  const float* gamma = (const float*)d_in[4];
  const float* beta  = (const float*)d_in[5];
  const float* mean  = (const float*)d_in[6];
  const float* var   = (const float*)d_in[7];
  const float* w2    = (const float*)d_in[8];
  const float* b2    = (const float*)d_in[9];
  const float* wv    = (const float*)d_in[10];
  const float* bv    = (const float*)d_in[11];
  float* out = (float*)d_out;

  hipLaunchKernelGGL(semca_fused, dim3(256), dim3(1024), 0, stream,
                     x, wk, bk, w1, gamma, beta, mean, var, w2, b2, wv, bv, out);
}

// Round 10
// 25.576 us; speedup vs baseline: 1.4860x; 1.0158x over previous
//
#include <hip/hip_runtime.h>

#define C 256
#define HW 81
#define PITCH 292   // ushorts per pixel row: [4 pad][256 ch][32 pad] (even dword pitch)
#define PITCHD 146  // dwords per pixel row; 146%32=18 -> gather tap bases ~4-apart
#define ZROW 81     // zeroed row index for invalid gather taps

typedef __fp16 h2 __attribute__((ext_vector_type(2)));  // matches builtin V2h

__device__ __forceinline__ float us2f(unsigned short u) {  // f16 bits -> f32
  union { unsigned short s; __fp16 h; } c; c.s = u; return (float)c.h;
}
__device__ __forceinline__ float lo_h(unsigned int d) {
  union { unsigned int i; h2 h; } c; c.i = d; return (float)c.h.x;
}
__device__ __forceinline__ float hi_h(unsigned int d) {
  union { unsigned int i; h2 h; } c; c.i = d; return (float)c.h.y;
}
__device__ __forceinline__ unsigned int pkh2(float a, float b) {  // 1x cvt_pkrtz
  union { h2 h; unsigned int i; } c;
  c.h = __builtin_amdgcn_cvt_pkrtz(a, b);
  return c.i;
}
__device__ __forceinline__ h2 as_h2(unsigned int d) {
  union { unsigned int i; h2 h; } c; c.i = d; return c.h;
}
__device__ __forceinline__ float dot2(unsigned int a, unsigned int b, float c) {
#if __has_builtin(__builtin_amdgcn_fdot2)
  return __builtin_amdgcn_fdot2(as_h2(a), as_h2(b), c, false);
#else
  h2 x = as_h2(a), y = as_h2(b);
  return fmaf((float)x.y, (float)y.y, fmaf((float)x.x, (float)y.x, c));
#endif
}
__device__ __forceinline__ float exp2_fast(float x) {
#if __has_builtin(__builtin_amdgcn_exp2f)
  return __builtin_amdgcn_exp2f(x);
#else
  return __expf(x * 0.6931471805599453f);
#endif
}

// ---------------------------------------------------------------------------
// Fully fused SeMCA. Block = (b, s): s=0 -> output rows 0..5, s=1 -> rows 6..8.
// 1024 threads = 4 instance-slots x 256 channels. 2 barriers.
// R10 (continuing R9's confirmed issue-bound mechanism; -~150 instr/thread):
//  - phase 1a via fdot2: even-channel pairs = stored dwords, odd-channel
//    pairs = 5 funnel-shifts (v_alignbit); wkp[81][6] half2 table (built in
//    0b under load shadow, incl (w8,0)/(0,w8) tails). 20 fdot2 + 5 align
//    replaces 12 cvt + 36 FMA per quad.
//  - softmax in exp2 domain: t = fma(a2, log2e, -mx*log2e); raw v_exp_f32.
//  - PV: acc = fma(acc, inv_s, k1) fold.
//  - w1/w2 fdot2 + f16 tables as in R9. LDS ~122 KiB, 1 block/CU.
// ---------------------------------------------------------------------------
__global__ __launch_bounds__(1024) void semca_fused(
    const float* __restrict__ x, const float* __restrict__ wk,
    const float* __restrict__ bk, const float* __restrict__ w1,
    const float* __restrict__ gamma, const float* __restrict__ beta,
    const float* __restrict__ mean, const float* __restrict__ var,
    const float* __restrict__ w2, const float* __restrict__ b2,
    const float* __restrict__ wv, const float* __restrict__ bv,
    float* __restrict__ out) {
  __shared__ unsigned short xT[82 * PITCH];   // 47,888 B (row 81 = zeros), f16
  __shared__ unsigned short k1T[82 * PITCH];  // 47,888 B (row 81 = zeros), f16
  __shared__ unsigned short vT[18 * PITCH];   // 10,512 B, f16
  __shared__ unsigned short pixtab[228];      //    456 B (premultiplied by PITCH)
  __shared__ float2 bnf[225];                 //  1,800 B
  __shared__ unsigned int w1p[225 * 12];      // 10,800 B half2 pairs, 48B/row
  __shared__ unsigned int w2p[225 * 4];       //  3,600 B half2 o-pairs (16B/row)
  __shared__ uint2 wkp[81 * 3];               //  1,944 B wk half2: 6 dwords/pixel

  const int blk = blockIdx.x;
  const int b = (blk & 7) * 16 + ((blk >> 3) & 15);  // XCD-paired, bijective
  const int s = blk >> 7;
  const int tid = threadIdx.x;
  const float* xb = x + (size_t)b * (C * HW);

  unsigned int* xTd = (unsigned int*)xT;
  unsigned int* k1Td = (unsigned int*)k1T;
  unsigned int* vTd = (unsigned int*)vT;
  unsigned int* wkpd = (unsigned int*)wkp;

  // ---- phase 0a: issue ALL x loads first (registers), incremental walk
  float xe[11], xo[11];
  int adr[11];
  {
    int chp = tid / HW;            // single division
    int p = tid - chp * HW;
#pragma unroll
    for (int rep = 0; rep < 10; ++rep) {
      const float* base = xb + (2 * chp) * HW + p;
      xe[rep] = base[0];
      xo[rep] = base[HW];
      adr[rep] = PITCHD * p + 2 + chp;
      chp += 12;                   // advance f by 1024 = 12*81 + 52
      p += 52;
      if (p >= HW) { p -= HW; chp += 1; }
    }
    if (tid < 128) {               // tail item f = 10240 + tid
      int f = 10240 + tid;
      int c2 = f / HW, p2 = f - c2 * HW;
      xe[10] = xb[2 * c2 * HW + p2];
      xo[10] = xb[(2 * c2 + 1) * HW + p2];
      adr[10] = PITCHD * p2 + 2 + c2;
    }
  }

  // ---- phase 0b: independent work under the load shadow
  for (int t = tid; t < 810; t += 1024) {  // x channel-pad zeros
    int p = t / 10, k2 = t - (t / 10) * 10;
    xT[p * PITCH + ((k2 < 4) ? k2 : (256 + k2))] = 0;
  }
  if (tid < PITCHD) {                      // zero row 81 of xT and k1T
    xTd[PITCHD * ZROW + tid] = 0;
    k1Td[PITCHD * ZROW + tid] = 0;
  }
  for (int t = tid; t < 225; t += 1024) {  // pixtab (premul) + folded BN
    int g = t / 9, tap = t - (t / 9) * 9;
    int kh = tap / 3, kw = tap - kh * 3;
    int h = kh * 5 + g / 5, w = kw * 5 + (g - (g / 5) * 5);
    pixtab[t] = (h < 9 && w < 9) ? (unsigned short)((h * 9 + w) * PITCH)
                                 : (unsigned short)(ZROW * PITCH);
    float inv = gamma[t] * rsqrtf(var[t] + 1e-5f);
    bnf[t] = make_float2(inv, beta[t] - mean[t] * inv);
  }
  for (int t = tid; t < 2025; t += 1024) {  // w1 packed pairs (x-tap, k1-tap)
    int m = t / 9, q = t - m * 9;
    w1p[m * 12 + q] = pkh2(w1[m * 18 + q], w1[m * 18 + 9 + q]);
  }
  if (tid < 900) {                          // w2 packed o-pairs (o=0..7)
    int m = tid >> 2, j = tid & 3;
    w2p[m * 4 + j] = pkh2(w2[m * 9 + 2 * j], w2[m * 9 + 2 * j + 1]);
  }
  if (tid < 486) {                          // wk packed pairs + tails
    int m = tid / 6, j = tid - (tid / 6) * 6;
    const float* wr = wk + m * 9;
    unsigned int v;
    if (j < 4)       v = pkh2(wr[2 * j], wr[2 * j + 1]);
    else if (j == 4) v = pkh2(wr[8], 0.f);
    else             v = pkh2(0.f, wr[8]);
    wkpd[m * 6 + j] = v;
  }

  // hoisted phase-1b weights: chv fixed per thread -> registers
  const int chv = tid & 127;
  float wv_e[9], wv_o[9];
#pragma unroll
  for (int t = 0; t < 9; ++t) {
    wv_e[t] = wv[(2 * chv) * 9 + t];
    wv_o[t] = wv[(2 * chv + 1) * 9 + t];
  }
  const float bv_e = bv[2 * chv], bv_o = bv[2 * chv + 1];

  // ---- phase 0c: pack (f16) + LDS write (single drain of the x loads)
#pragma unroll
  for (int rep = 0; rep < 10; ++rep) xTd[adr[rep]] = pkh2(xe[rep], xo[rep]);
  if (tid < 128) xTd[adr[10]] = pkh2(xe[10], xo[10]);

  __syncthreads();

  // ---- phase 1a: k1[p][ch] = sum_j x[p][ch+j-4]*wk[p][j] + bk[p]
  // quad u: window = dwords 2u..2u+5 from row base (halo via pads).
  // even channels use stored dwords as pairs; odd channels use funnel-
  // shifted pairs (v_alignbit). 20 fdot2 per quad, f32 accumulation.
  {
    auto k1fn = [&](int f) {
      int p = __builtin_amdgcn_readfirstlane(f >> 6);
      int u = f & 63;  // channel quad index
      const uint2* wrow2 = (const uint2*)(xTd + PITCHD * p);
      uint2 q0 = wrow2[u], q1 = wrow2[u + 1], q2 = wrow2[u + 2];
      unsigned int D0 = q0.x, D1 = q0.y, D2 = q1.x, D3 = q1.y,
                   D4 = q2.x, D5 = q2.y;
      unsigned int A0 = (D0 >> 16) | (D1 << 16);
      unsigned int A1 = (D1 >> 16) | (D2 << 16);
      unsigned int A2 = (D2 >> 16) | (D3 << 16);
      unsigned int A3 = (D3 >> 16) | (D4 << 16);
      unsigned int A4 = (D4 >> 16) | (D5 << 16);
      const uint2* wkq = wkp + p * 3;
      uint2 wa = wkq[0], wb = wkq[1], wc = wkq[2];
      // wa.x=(w0,w1) wa.y=(w2,w3) wb.x=(w4,w5) wb.y=(w6,w7)
      // wc.x=(w8,0)  wc.y=(0,w8)
      float bkp = bk[p];
      float c0 = dot2(D0, wa.x, dot2(D1, wa.y, dot2(D2, wb.x,
                 dot2(D3, wb.y, dot2(D4, wc.x, bkp)))));
      float c1 = dot2(A0, wa.x, dot2(A1, wa.y, dot2(A2, wb.x,
                 dot2(A3, wb.y, dot2(D4, wc.y, bkp)))));
      float c2 = dot2(D1, wa.x, dot2(D2, wa.y, dot2(D3, wb.x,
                 dot2(D4, wb.y, dot2(D5, wc.x, bkp)))));
      float c3 = dot2(A1, wa.x, dot2(A2, wa.y, dot2(A3, wb.x,
                 dot2(A4, wb.y, dot2(D5, wc.y, bkp)))));
      *(uint2*)(k1Td + PITCHD * p + 2 + 2 * u) =
          make_uint2(pkh2(c0, c1), pkh2(c2, c3));
    };
#pragma unroll
    for (int rep = 0; rep < 5; ++rep) k1fn(tid + rep * 1024);
    if (tid < 64) k1fn(5120 + tid);
  }

  // ---- phase 1b: v (3x3 depthwise) at the 18 pixels this half needs
  {
    auto vfn = [&](int f) {
      int e = __builtin_amdgcn_readfirstlane(f >> 7);  // 0..17 uniform
      int r0 = e / 6;
      int i = s * 3 + r0;  // v-pixel row 0..5
      int j = e - r0 * 6;  // v-pixel col 0..5
      float a_e = bv_e, a_o = bv_o;
#pragma unroll
      for (int di = 0; di < 3; ++di) {
        int ii = i + di - 1;
        if (ii < 0) continue;  // ii <= 6 < 9 always
#pragma unroll
        for (int dj = 0; dj < 3; ++dj) {
          int jj = j + dj - 1;
          if (jj < 0) continue;  // jj <= 6 < 9 always
          unsigned int d = xTd[PITCHD * (ii * 9 + jj) + 2 + chv];
          int t = di * 3 + dj;
          a_e = fmaf(lo_h(d), wv_e[t], a_e);
          a_o = fmaf(hi_h(d), wv_o[t], a_o);
        }
      }
      vTd[PITCHD * e + 2 + chv] = pkh2(a_e, a_o);
    };
#pragma unroll
    for (int rep = 0; rep < 2; ++rep) vfn(tid + rep * 1024);
    if (tid < 256) vfn(2048 + tid);
  }
  if (tid < 180) {  // vT channel-pad zeros
    int e = tid / 10, k2 = tid - (tid / 10) * 10;
    vT[e * PITCH + ((k2 < 4) ? k2 : (256 + k2))] = 0;
  }
  __syncthreads();

  // ---- phase 2: 15 deduped instances; 4 slots x 4 unrolled iterations
  const int s4 = tid >> 8;  // slot 0..3 (wave-uniform)
  const int ch = tid & 255;
  const int ci0 = ch / 9;
  const int tap0 = ch - ci0 * 9;
  float* outb = out + ((size_t)b * C + ch) * HW;

  // per-lane gather walk is instance-invariant
  int tq[9], cq[9];
  {
    int ci = ci0, tap = tap0;
#pragma unroll
    for (int q = 0; q < 9; ++q) {
      tq[q] = tap;
      cq[q] = 4 + ci;
      tap += 4;
      ci += 28;
      if (tap >= 9) { tap -= 9; ci += 1; }
    }
  }

#define PV_STORE(OH, OW)                                                   \
  do {                                                                     \
    int e_ = gh_i * 6 + ((OW)-3);                                          \
    const unsigned short* vrow_ = vT + e_ * PITCH;                         \
    float acc_ = 0.f;                                                      \
    _Pragma("unroll") for (int d_ = 0; d_ < 9; ++d_) acc_ =                \
        fmaf(a2[d_], us2f(vrow_[ch + d_]), acc_);                          \
    if ((OH) < 6 && (OW) < 6)                                              \
      acc_ = fmaf(acc_, inv_s,                                             \
                  us2f(k1T[(((OH) + 3) * 9 + ((OW) + 3)) * PITCH + 4 + ch])); \
    else                                                                   \
      acc_ *= inv_s;                                                       \
    if (valid_inst) outb[(OH)*9 + (OW)] = acc_;                            \
  } while (0)

#pragma unroll
  for (int k = 0; k < 4; ++k) {
    int idx = s4 * 4 + k;
    const bool valid_inst = (idx < 15);
    if (!valid_inst) idx = 14;  // dummy recomputes a real instance, no store
    int gh_i = idx / 5, gw_i = idx - (idx / 5) * 5;
    int oh = (s ? 6 : 3) + gh_i;
    int gh = s ? ((gh_i + 4) % 5) : (gh_i + 1);
    int g9 = __builtin_amdgcn_readfirstlane((gh * 5 + gw_i) * 9);

    // kq gather -> packed half2 (x_q, k1_q): 2 u16 reads + 1 lshl_or per q
    unsigned int kqp[9];
#pragma unroll
    for (int q = 0; q < 9; ++q) {
      int off = (int)pixtab[g9 + tq[q]] + cq[q];
      unsigned int xv = xT[off], kv = k1T[off];
      kqp[q] = xv | (kv << 16);
    }

    __builtin_amdgcn_s_setprio(1);
    // w1 (packed pairs, fdot2) -> folded BN -> ReLU
    float r[9];
#pragma unroll
    for (int o = 0; o < 9; ++o) {
      int m = g9 + o;
      const unsigned int* wp = w1p + m * 12;
      float a = 0.f;
#pragma unroll
      for (int q = 0; q < 9; ++q) a = dot2(kqp[q], wp[q], a);
      float2 bn = bnf[m];
      a = fmaf(a, bn.x, bn.y);
      r[o] = fmaxf(a, 0.f);
    }

    // w2 (packed o-pairs, fdot2) + b2 -> softmax in exp2 domain
    unsigned int rp[4];
#pragma unroll
    for (int j = 0; j < 4; ++j) rp[j] = pkh2(r[2 * j], r[2 * j + 1]);
    float a2[9], mx = -1e30f;
#pragma unroll
    for (int d = 0; d < 9; ++d) {
      int m = g9 + d;
      const unsigned int* wq = w2p + m * 4;
      float a = b2[m];
#pragma unroll
      for (int j = 0; j < 4; ++j) a = dot2(rp[j], wq[j], a);
      a = fmaf(w2[m * 9 + 8], r[8], a);
      a2[d] = a;
      mx = fmaxf(mx, a);
    }
    const float L2E = 1.44269504f;
    float nmL = mx * -L2E;
    float ssum = 0.f;
#pragma unroll
    for (int d = 0; d < 9; ++d) {
      a2[d] = exp2_fast(fmaf(a2[d], L2E, nmL));
      ssum += a2[d];
    }
    float inv_s = __builtin_amdgcn_rcpf(ssum);
    __builtin_amdgcn_s_setprio(0);

    // PV + k1-add + store; gw==1 serves both ow=3 and ow=8
    int ow0 = (gw_i == 0) ? 7 : (gw_i + 2);
    PV_STORE(oh, ow0);
    if (gw_i == 1) PV_STORE(oh, 8);
  }
#undef PV_STORE

  // ---- epilogue: non-PV output pixels
  if (s == 0) {
    if (s4 < 3) {
      int oh = s4;  // rows 0..2: k1 where ow<6, else 0
#pragma unroll
      for (int ow = 0; ow < 9; ++ow) {
        float v2 = 0.f;
        if (ow < 6)
          v2 = us2f(k1T[((oh + 3) * 9 + (ow + 3)) * PITCH + 4 + ch]);
        outb[oh * 9 + ow] = v2;
      }
    } else {
      // rows 3..5, cols 0..2: k1-only
#pragma unroll
      for (int r0 = 0; r0 < 3; ++r0) {
        int oh = 3 + r0;
#pragma unroll
        for (int ow = 0; ow < 3; ++ow)
          outb[oh * 9 + ow] =
              us2f(k1T[((oh + 3) * 9 + (ow + 3)) * PITCH + 4 + ch]);
      }
    }
  } else if (s4 < 3) {
    int oh = 6 + s4;  // rows 6..8, cols 0..2: zero
    outb[oh * 9 + 0] = 0.f;
    outb[oh * 9 + 1] = 0.f;
    outb[oh * 9 + 2] = 0.f;
  }
}

extern "C" void kernel_launch(void* const* d_in, const int* in_sizes, int n_in,
                              void* d_out, int out_size, void* d_ws, size_t ws_size,
                              hipStream_t stream) {
  const float* x     = (const float*)d_in[0];
  const float* wk    = (const float*)d_in[1];
  const float* bk    = (const float*)d_in[2];
  const float* w1    = (const float*)d_in[3];
  const float* gamma = (const float*)d_in[4];
  const float* beta  = (const float*)d_in[5];
  const float* mean  = (const float*)d_in[6];
  const float* var   = (const float*)d_in[7];
  const float* w2    = (const float*)d_in[8];
  const float* b2    = (const float*)d_in[9];
  const float* wv    = (const float*)d_in[10];
  const float* bv    = (const float*)d_in[11];
  float* out = (float*)d_out;

  hipLaunchKernelGGL(semca_fused, dim3(256), dim3(1024), 0, stream,
                     x, wk, bk, w1, gamma, beta, mean, var, w2, b2, wv, bv, out);
}